// Round 3
// baseline (1895.588 us; speedup 1.0000x reference)
//
#include <hip/hip_runtime.h>
#include <math.h>

#define NPTS 4096
#define MC   1024
#define KNB  32

typedef __attribute__((ext_vector_type(8))) short bf16x8;
typedef __attribute__((ext_vector_type(4))) float f32x4;

__device__ __forceinline__ unsigned short f2bf(float f) {
  unsigned int u = __float_as_uint(f);
  u = u + 0x7fffu + ((u >> 16) & 1u);   // round-to-nearest-even
  return (unsigned short)(u >> 16);
}

template <int CTRL>
__device__ __forceinline__ float dpp_max(float v) {
  int o = __builtin_amdgcn_update_dpp(__float_as_int(v), __float_as_int(v), CTRL, 0xF, 0xF, false);
  return fmaxf(v, __int_as_float(o));
}

// static-index 16->1 mux by mj bits (all indices compile-time -> stays in VGPRs)
#define MUX16(res, A)                                                     \
  {                                                                       \
    float p0 = s0_ ? A[1] : A[0],   p1 = s0_ ? A[3] : A[2];               \
    float p2 = s0_ ? A[5] : A[4],   p3 = s0_ ? A[7] : A[6];               \
    float p4 = s0_ ? A[9] : A[8],   p5 = s0_ ? A[11] : A[10];             \
    float p6 = s0_ ? A[13] : A[12], p7 = s0_ ? A[15] : A[14];             \
    float q0 = s1_ ? p1 : p0, q1 = s1_ ? p3 : p2;                         \
    float q2 = s1_ ? p5 : p4, q3 = s1_ ? p7 : p6;                         \
    float r0 = s2_ ? q1 : q0, r1 = s2_ ? q3 : q2;                         \
    res = s3_ ? r1 : r0;                                                  \
  }

// ---------------------------------------------------------------------------
// Kernel 1 (fused): blocks 0..7 = FPS (TWO batches per block), 8..1031 =
// feature transpose, 1032..1040 = weight pack.
//
// FPS R6: pair two independent batches per block to amortize the per-
// iteration sync phase (measured ~1300 cyc: DPP chain + readlane + key
// publish + barrier + LDS read + tournament + coord fetch) over two FPS
// iterations, since the update phase is only ~320 cyc (R0 vs R1 delta).
// Structure per iteration: update A (16 pts/lane) -> update B -> wave value
// max via DPP + readlane + ONE ballot each (lane-major ownership: lane t
// owns pts [16t,16t+16) so lowest lane = lowest gidx) -> winner lanes mux
// coords out of their own registers (static cndmask tree, R2-proven) and
// publish {key, x, y, z} to parity-double-buffered LDS slots -> ONE barrier
// -> all lanes read all 8 key+payload slots in one parallel (non-volatile!)
// LDS round -> 4-way key tournament with coord payload per batch. No
// volatile, no spin (R2's failure was volatile-serialized LDS reads), no
// second dependent LDS trip, no 96KB coord staging (LDS ~25KB -> transpose
// blocks co-reside freely).
// Exact jnp.argmax tie-break semantics: strict-gt in-lane keeps lowest j;
// lane-major => wave-min-lane = min gidx; ~gidx in key low word => u64 max
// = max dist then min gidx across waves; dist math bit-exact _rn.
// ---------------------------------------------------------------------------
struct FpsShared {
  unsigned long long key[2][2][4];   // [batch][parity][wave]: distbits<<32 | ~gidx
  unsigned long long cxy[2][2][4];   // bits(y)<<32 | bits(x)
  float              cz [2][2][4];
  float slog[2][3][MC];
};
struct TransShared {
  float tile[64][65];
};

__global__ __launch_bounds__(256, 1) void fused_pre(
    const float* __restrict__ points, const float* __restrict__ feats,
    const float* __restrict__ w1, const float* __restrict__ w2,
    const float* __restrict__ w3,
    unsigned short* __restrict__ featsT, unsigned short* __restrict__ wpack,
    float* __restrict__ out_cent) {
  __shared__ union { FpsShared f; TransShared tr; } S;
  const int blk = blockIdx.x;
  const int t = threadIdx.x;

  if (blk < 8) {
    // ======================= FPS (batches 2*blk, 2*blk+1) =======================
    const int w = t >> 6, lane = t & 63;
    const float* pA = points + (size_t)(2 * blk)     * 3 * NPTS;
    const float* pB = points + (size_t)(2 * blk + 1) * 3 * NPTS;

    // lane-major: thread t owns global pts [16t, 16t+16); j = 4c+u
    float Ax[16], Ay[16], Az[16], Ad[16];
    float Bx[16], By[16], Bz[16], Bd[16];
#pragma unroll
    for (int c = 0; c < 4; ++c) {
      float4 X = ((const float4*)pA)[t * 4 + c];
      float4 Y = ((const float4*)(pA + NPTS))[t * 4 + c];
      float4 Z = ((const float4*)(pA + 2 * NPTS))[t * 4 + c];
      Ax[c * 4 + 0] = X.x; Ax[c * 4 + 1] = X.y; Ax[c * 4 + 2] = X.z; Ax[c * 4 + 3] = X.w;
      Ay[c * 4 + 0] = Y.x; Ay[c * 4 + 1] = Y.y; Ay[c * 4 + 2] = Y.z; Ay[c * 4 + 3] = Y.w;
      Az[c * 4 + 0] = Z.x; Az[c * 4 + 1] = Z.y; Az[c * 4 + 2] = Z.z; Az[c * 4 + 3] = Z.w;
      float4 X2 = ((const float4*)pB)[t * 4 + c];
      float4 Y2 = ((const float4*)(pB + NPTS))[t * 4 + c];
      float4 Z2 = ((const float4*)(pB + 2 * NPTS))[t * 4 + c];
      Bx[c * 4 + 0] = X2.x; Bx[c * 4 + 1] = X2.y; Bx[c * 4 + 2] = X2.z; Bx[c * 4 + 3] = X2.w;
      By[c * 4 + 0] = Y2.x; By[c * 4 + 1] = Y2.y; By[c * 4 + 2] = Y2.z; By[c * 4 + 3] = Y2.w;
      Bz[c * 4 + 0] = Z2.x; Bz[c * 4 + 1] = Z2.y; Bz[c * 4 + 2] = Z2.z; Bz[c * 4 + 3] = Z2.w;
    }
#pragma unroll
    for (int j = 0; j < 16; ++j) { Ad[j] = 1e10f; Bd[j] = 1e10f; }

    float lxA = pA[0], lyA = pA[NPTS], lzA = pA[2 * NPTS];
    float lxB = pB[0], lyB = pB[NPTS], lzB = pB[2 * NPTS];

    for (int i = 0; i < MC; ++i) {
      if (t == 0)  { S.f.slog[0][0][i] = lxA; S.f.slog[0][1][i] = lyA; S.f.slog[0][2][i] = lzA; }
      if (t == 64) { S.f.slog[1][0][i] = lxB; S.f.slog[1][1][i] = lyB; S.f.slog[1][2][i] = lzB; }
      if (i == MC - 1) break;

      // ---- update A (bit-exact) + in-lane (max, lowest-j) ----
      float mA = -1.0f; int jA = 0;
#pragma unroll
      for (int j = 0; j < 16; ++j) {
        float dx = __fsub_rn(Ax[j], lxA);
        float dy = __fsub_rn(Ay[j], lyA);
        float dz = __fsub_rn(Az[j], lzA);
        float d  = __fadd_rn(__fadd_rn(__fmul_rn(dx, dx), __fmul_rn(dy, dy)), __fmul_rn(dz, dz));
        float dm = fminf(Ad[j], d);
        Ad[j] = dm;
        bool gt = dm > mA;   // strict: keeps lowest j on ties
        mA = gt ? dm : mA;
        jA = gt ? j  : jA;
      }
      // ---- update B ----
      float mB = -1.0f; int jB = 0;
#pragma unroll
      for (int j = 0; j < 16; ++j) {
        float dx = __fsub_rn(Bx[j], lxB);
        float dy = __fsub_rn(By[j], lyB);
        float dz = __fsub_rn(Bz[j], lzB);
        float d  = __fadd_rn(__fadd_rn(__fmul_rn(dx, dx), __fmul_rn(dy, dy)), __fmul_rn(dz, dz));
        float dm = fminf(Bd[j], d);
        Bd[j] = dm;
        bool gt = dm > mB;
        mB = gt ? dm : mB;
        jB = gt ? j  : jB;
      }

      // ---- wave value max via DPP (valid in lane 63), both batches ----
      float ra = mA, rb = mB;
      ra = dpp_max<0x111>(ra); rb = dpp_max<0x111>(rb);   // row_shr:1
      ra = dpp_max<0x112>(ra); rb = dpp_max<0x112>(rb);   // row_shr:2
      ra = dpp_max<0x114>(ra); rb = dpp_max<0x114>(rb);   // row_shr:4
      ra = dpp_max<0x118>(ra); rb = dpp_max<0x118>(rb);   // row_shr:8
      ra = dpp_max<0x142>(ra); rb = dpp_max<0x142>(rb);   // row_bcast:15
      ra = dpp_max<0x143>(ra); rb = dpp_max<0x143>(rb);   // row_bcast:31
      const float wvA = __int_as_float(__builtin_amdgcn_readlane(__float_as_int(ra), 63));
      const float wvB = __int_as_float(__builtin_amdgcn_readlane(__float_as_int(rb), 63));

      // ---- winner lane = lowest lane achieving wv (lane-major => lowest gidx) ----
      const unsigned long long ballA = __ballot(mA == wvA);
      const unsigned long long ballB = __ballot(mB == wvB);
      const int wlA = __ffsll((long long)ballA) - 1;
      const int wlB = __ffsll((long long)ballB) - 1;
      const int par = i & 1;

      if (lane == wlA) {
        const bool s0_ = jA & 1, s1_ = jA & 2, s2_ = jA & 4, s3_ = jA & 8;
        float wx, wy, wz;
        MUX16(wx, Ax); MUX16(wy, Ay); MUX16(wz, Az);
        const unsigned int gidx = (unsigned int)(t * 16 + jA);
        S.f.key[0][par][w] = ((unsigned long long)__float_as_uint(mA) << 32) | (unsigned int)~gidx;
        S.f.cxy[0][par][w] = ((unsigned long long)__float_as_uint(wy) << 32) | __float_as_uint(wx);
        S.f.cz [0][par][w] = wz;
      }
      if (lane == wlB) {
        const bool s0_ = jB & 1, s1_ = jB & 2, s2_ = jB & 4, s3_ = jB & 8;
        float wx, wy, wz;
        MUX16(wx, Bx); MUX16(wy, By); MUX16(wz, Bz);
        const unsigned int gidx = (unsigned int)(t * 16 + jB);
        S.f.key[1][par][w] = ((unsigned long long)__float_as_uint(mB) << 32) | (unsigned int)~gidx;
        S.f.cxy[1][par][w] = ((unsigned long long)__float_as_uint(wy) << 32) | __float_as_uint(wx);
        S.f.cz [1][par][w] = wz;
      }
      __syncthreads();

      // ---- one parallel LDS read of all 8 slots, then payload tournaments ----
      {
        unsigned long long k0 = S.f.key[0][par][0], k1 = S.f.key[0][par][1];
        unsigned long long k2 = S.f.key[0][par][2], k3 = S.f.key[0][par][3];
        unsigned long long x0 = S.f.cxy[0][par][0], x1 = S.f.cxy[0][par][1];
        unsigned long long x2 = S.f.cxy[0][par][2], x3 = S.f.cxy[0][par][3];
        float z0 = S.f.cz[0][par][0], z1 = S.f.cz[0][par][1];
        float z2 = S.f.cz[0][par][2], z3 = S.f.cz[0][par][3];
        const bool g1 = k1 > k0;
        const unsigned long long ka = g1 ? k1 : k0, xa = g1 ? x1 : x0; const float za = g1 ? z1 : z0;
        const bool g2 = k3 > k2;
        const unsigned long long kb = g2 ? k3 : k2, xb = g2 ? x3 : x2; const float zb = g2 ? z3 : z2;
        const bool g3 = kb > ka;
        const unsigned long long xw = g3 ? xb : xa;
        lxA = __uint_as_float((unsigned int)xw);
        lyA = __uint_as_float((unsigned int)(xw >> 32));
        lzA = g3 ? zb : za;
      }
      {
        unsigned long long k0 = S.f.key[1][par][0], k1 = S.f.key[1][par][1];
        unsigned long long k2 = S.f.key[1][par][2], k3 = S.f.key[1][par][3];
        unsigned long long x0 = S.f.cxy[1][par][0], x1 = S.f.cxy[1][par][1];
        unsigned long long x2 = S.f.cxy[1][par][2], x3 = S.f.cxy[1][par][3];
        float z0 = S.f.cz[1][par][0], z1 = S.f.cz[1][par][1];
        float z2 = S.f.cz[1][par][2], z3 = S.f.cz[1][par][3];
        const bool g1 = k1 > k0;
        const unsigned long long ka = g1 ? k1 : k0, xa = g1 ? x1 : x0; const float za = g1 ? z1 : z0;
        const bool g2 = k3 > k2;
        const unsigned long long kb = g2 ? k3 : k2, xb = g2 ? x3 : x2; const float zb = g2 ? z3 : z2;
        const bool g3 = kb > ka;
        const unsigned long long xw = g3 ? xb : xa;
        lxB = __uint_as_float((unsigned int)xw);
        lyB = __uint_as_float((unsigned int)(xw >> 32));
        lzB = g3 ? zb : za;
      }
    }
    __syncthreads();
    // coalesced centroid output [3][1024] per batch
    float* ocA = out_cent + (size_t)(2 * blk)     * 3 * MC;
    float* ocB = out_cent + (size_t)(2 * blk + 1) * 3 * MC;
#pragma unroll
    for (int k = 0; k < 12; ++k) {
      int idx = t + k * 256;
      ocA[idx] = ((const float*)S.f.slog[0])[idx];
      ocB[idx] = ((const float*)S.f.slog[1])[idx];
    }
  } else if (blk < 8 + 1024) {
    // ================== feature transpose ==================
    const int rel = blk - 8;
    const int b = rel >> 6;
    const int n0 = (rel & 63) * 64;
    const float* src = feats + (size_t)b * 64 * NPTS;
    {
      const int n = t & 63, cbase = t >> 6;
#pragma unroll
      for (int j = 0; j < 16; ++j) {
        int cc = cbase + j * 4;
        S.tr.tile[cc][n] = src[(size_t)cc * NPTS + n0 + n];
      }
    }
    __syncthreads();
    {
      const int cc = t & 63, nbase = t >> 6;
      unsigned short* dst = featsT + ((size_t)b * NPTS + n0) * 64;
#pragma unroll
      for (int j = 0; j < 16; ++j) {
        int n = nbase + j * 4;
        dst[(size_t)n * 64 + cc] = f2bf(S.tr.tile[cc][n]);
      }
    }
  } else {
    // ================== weight pack (f = 0..35) ==================
    const int f = (blk - (8 + 1024)) * 4 + (t >> 6);
    const int lane = t & 63;
    if (f < 36) {
      int layer, kt, nt;
      if (f < 12)      { layer = 0; kt = f >> 2;        nt = f & 3; }
      else if (f < 20) { layer = 1; kt = (f - 12) >> 2; nt = (f - 12) & 3; }
      else             { layer = 2; kt = (f - 20) >> 3; nt = (f - 20) & 7; }
      const int o = nt * 16 + (lane & 15);
      unsigned short* dst = wpack + ((size_t)f * 64 + lane) * 8;
#pragma unroll
      for (int j = 0; j < 8; ++j) {
        int k = kt * 32 + (lane >> 4) * 8 + j;
        float x = 0.0f;
        if (layer == 0)      { if (k < 67) { int cin = (k < 64) ? (k + 3) : (k - 64); x = w1[o * 67 + cin]; } }
        else if (layer == 1) { x = w2[o * 64 + k]; }
        else                 { x = w3[o * 64 + k]; }
        dst[j] = f2bf(x);
      }
    }
  }
}

// ---------------------------------------------------------------------------
// Kernel 2: ball query. Centroids read from out_cent layout [B,3,MC].
// ---------------------------------------------------------------------------
__global__ __launch_bounds__(256) void ball_query_kernel(const float* __restrict__ points,
                                                         const float* __restrict__ cent,
                                                         int* __restrict__ nidx) {
  __shared__ float sx[NPTS], sy[NPTS], sz[NPTS];
  __shared__ int lists[4][KNB];
  const int b  = blockIdx.x >> 4;
  const int cb = blockIdx.x & 15;
  const int t = threadIdx.x;
  const float* pb = points + (size_t)b * 3 * NPTS;
#pragma unroll
  for (int j = 0; j < 4; ++j) {
    int i4 = t + j * 256;
    ((float4*)sx)[i4] = ((const float4*)pb)[i4];
    ((float4*)sy)[i4] = ((const float4*)(pb + NPTS))[i4];
    ((float4*)sz)[i4] = ((const float4*)(pb + 2 * NPTS))[i4];
  }
  __syncthreads();
  const int w = t >> 6, lane = t & 63;
  const float R2 = (float)(0.2 * 0.2);
  const float* cbp = cent + (size_t)b * 3 * MC;
  for (int cm = 0; cm < 16; ++cm) {
    const int m  = cb * 64 + w * 16 + cm;
    const int bm = b * MC + m;
    const float cx = cbp[m], cy = cbp[MC + m], cz = cbp[2 * MC + m];
    const float c2 = __fadd_rn(__fadd_rn(__fmul_rn(cx, cx), __fmul_rn(cy, cy)), __fmul_rn(cz, cz));
    int cnt = 0;
    for (int ch = 0; ch < 64; ++ch) {
      const int n = ch * 64 + lane;
      float x = sx[n], y = sy[n], z = sz[n];
      float p2  = __fadd_rn(__fadd_rn(__fmul_rn(x, x),  __fmul_rn(y, y)),  __fmul_rn(z, z));
      float dot = __fadd_rn(__fadd_rn(__fmul_rn(cx, x), __fmul_rn(cy, y)), __fmul_rn(cz, z));
      float d2  = __fsub_rn(__fadd_rn(c2, p2), __fmul_rn(2.0f, dot));
      bool hit = (d2 <= R2);
      unsigned long long msk = __ballot(hit);
      if (hit) {
        int pos = cnt + __popcll(msk & ((1ull << lane) - 1ull));
        if (pos < KNB) lists[w][pos] = n;
      }
      cnt += __popcll(msk);
      if (cnt >= KNB) break;
    }
    if (lane < KNB) {
      int first = lists[w][0];
      int v = (lane < cnt) ? lists[w][lane] : first;
      nidx[(size_t)bm * KNB + lane] = v;
    }
  }
}

// ---------------------------------------------------------------------------
// Kernel 3: fused gather + 3-layer MLP (bf16 MFMA 16x16x32) + maxpool.
// ---------------------------------------------------------------------------
__global__ __launch_bounds__(256) void mlp_kernel(
    const float* __restrict__ points,
    const float* __restrict__ cent,
    const int* __restrict__ nidx,
    const unsigned short* __restrict__ featsT,
    const unsigned short* __restrict__ wpack,
    const float* __restrict__ b1, const float* __restrict__ g1, const float* __restrict__ be1,
    const float* __restrict__ b2, const float* __restrict__ g2, const float* __restrict__ be2,
    const float* __restrict__ b3, const float* __restrict__ g3, const float* __restrict__ be3,
    float* __restrict__ out) {
  __shared__ __align__(16) unsigned short Hs[4][2][32 * 72];
  __shared__ __align__(16) float obuf[128 * 20];
  const int t = threadIdx.x;
  const int w = t >> 6, lane = t & 63;
  const int r = lane & 15, q = lane >> 4;
  const float inv_s = 1.0f / sqrtf(1.0f + 1e-5f);

  float pb1[4], ps1[4], pe1[4], pb2[4], ps2[4], pe2[4], pb3[8], ps3[8], pe3[8];
#pragma unroll
  for (int nt = 0; nt < 4; ++nt) {
    int o = nt * 16 + r;
    pb1[nt] = b1[o]; ps1[nt] = g1[o] * inv_s; pe1[nt] = be1[o];
    pb2[nt] = b2[o]; ps2[nt] = g2[o] * inv_s; pe2[nt] = be2[o];
  }
#pragma unroll
  for (int nt = 0; nt < 8; ++nt) {
    int o = nt * 16 + r;
    pb3[nt] = b3[o]; ps3[nt] = g3[o] * inv_s; pe3[nt] = be3[o];
  }
  const int bm0 = blockIdx.x * 16;
  const int b   = bm0 >> 10;
  const int m0  = bm0 & 1023;
  const float* ptsb = points + (size_t)b * 3 * NPTS;
  const float* cbp  = cent + (size_t)b * 3 * MC;

  for (int it = 0; it < 4; ++it) {
    const int ml = it * 4 + w;
    const int bm = bm0 + ml;
    const int m  = bm & 1023;
    const int n0 = nidx[(size_t)bm * KNB + r];
    const int n1 = nidx[(size_t)bm * KNB + 16 + r];
    const float cx = cbp[m], cy = cbp[MC + m], cz = cbp[2 * MC + m];

    // ---- layer 1 ----
    bf16x8 aF[2][2];
#pragma unroll
    for (int mt = 0; mt < 2; ++mt) {
      int n = mt ? n1 : n0;
      const unsigned short* rowp = featsT + ((size_t)b * NPTS + n) * 64 + q * 8;
      aF[mt][0] = *(const bf16x8*)(rowp);
      aF[mt][1] = *(const bf16x8*)(rowp + 32);
    }
    bf16x8 aL[2];
#pragma unroll
    for (int mt = 0; mt < 2; ++mt) {
      bf16x8 a = {0, 0, 0, 0, 0, 0, 0, 0};
      if (q == 0) {
        int n = mt ? n1 : n0;
        a[0] = (short)f2bf(ptsb[n] - cx);
        a[1] = (short)f2bf(ptsb[NPTS + n] - cy);
        a[2] = (short)f2bf(ptsb[2 * NPTS + n] - cz);
      }
      aL[mt] = a;
    }
    f32x4 acc1[2][4];
#pragma unroll
    for (int mt = 0; mt < 2; ++mt)
#pragma unroll
      for (int nt = 0; nt < 4; ++nt) acc1[mt][nt] = (f32x4){0.f, 0.f, 0.f, 0.f};
#pragma unroll
    for (int kt = 0; kt < 3; ++kt) {
#pragma unroll
      for (int nt = 0; nt < 4; ++nt) {
        bf16x8 wf = *(const bf16x8*)(wpack + ((size_t)(kt * 4 + nt) * 64 + lane) * 8);
#pragma unroll
        for (int mt = 0; mt < 2; ++mt) {
          bf16x8 a = (kt < 2) ? aF[mt][kt] : aL[mt];
          acc1[mt][nt] = __builtin_amdgcn_mfma_f32_16x16x32_bf16(a, wf, acc1[mt][nt], 0, 0, 0);
        }
      }
    }
#pragma unroll
    for (int mt = 0; mt < 2; ++mt)
#pragma unroll
      for (int nt = 0; nt < 4; ++nt)
#pragma unroll
        for (int rr = 0; rr < 4; ++rr) {
          float y = (acc1[mt][nt][rr] + pb1[nt]) * ps1[nt] + pe1[nt];
          y = fmaxf(y, 0.0f);
          Hs[w][0][(mt * 16 + q * 4 + rr) * 72 + nt * 16 + r] = f2bf(y);
        }
    __threadfence_block();

    // ---- layer 2 ----
    f32x4 acc2[2][4];
#pragma unroll
    for (int mt = 0; mt < 2; ++mt)
#pragma unroll
      for (int nt = 0; nt < 4; ++nt) acc2[mt][nt] = (f32x4){0.f, 0.f, 0.f, 0.f};
#pragma unroll
    for (int kt = 0; kt < 2; ++kt) {
      bf16x8 a0 = *(const bf16x8*)&Hs[w][0][(0 * 16 + r) * 72 + kt * 32 + q * 8];
      bf16x8 a1 = *(const bf16x8*)&Hs[w][0][(1 * 16 + r) * 72 + kt * 32 + q * 8];
#pragma unroll
      for (int nt = 0; nt < 4; ++nt) {
        bf16x8 wf = *(const bf16x8*)(wpack + ((size_t)(12 + kt * 4 + nt) * 64 + lane) * 8);
        acc2[0][nt] = __builtin_amdgcn_mfma_f32_16x16x32_bf16(a0, wf, acc2[0][nt], 0, 0, 0);
        acc2[1][nt] = __builtin_amdgcn_mfma_f32_16x16x32_bf16(a1, wf, acc2[1][nt], 0, 0, 0);
      }
    }
#pragma unroll
    for (int mt = 0; mt < 2; ++mt)
#pragma unroll
      for (int nt = 0; nt < 4; ++nt)
#pragma unroll
        for (int rr = 0; rr < 4; ++rr) {
          float y = (acc2[mt][nt][rr] + pb2[nt]) * ps2[nt] + pe2[nt];
          y = fmaxf(y, 0.0f);
          Hs[w][1][(mt * 16 + q * 4 + rr) * 72 + nt * 16 + r] = f2bf(y);
        }
    __threadfence_block();

    // ---- layer 3 + maxpool ----
    f32x4 acc3[2][8];
#pragma unroll
    for (int mt = 0; mt < 2; ++mt)
#pragma unroll
      for (int nt = 0; nt < 8; ++nt) acc3[mt][nt] = (f32x4){0.f, 0.f, 0.f, 0.f};
#pragma unroll
    for (int kt = 0; kt < 2; ++kt) {
      bf16x8 a0 = *(const bf16x8*)&Hs[w][1][(0 * 16 + r) * 72 + kt * 32 + q * 8];
      bf16x8 a1 = *(const bf16x8*)&Hs[w][1][(1 * 16 + r) * 72 + kt * 32 + q * 8];
#pragma unroll
      for (int nt = 0; nt < 8; ++nt) {
        bf16x8 wf = *(const bf16x8*)(wpack + ((size_t)(20 + kt * 8 + nt) * 64 + lane) * 8);
        acc3[0][nt] = __builtin_amdgcn_mfma_f32_16x16x32_bf16(a0, wf, acc3[0][nt], 0, 0, 0);
        acc3[1][nt] = __builtin_amdgcn_mfma_f32_16x16x32_bf16(a1, wf, acc3[1][nt], 0, 0, 0);
      }
    }
#pragma unroll
    for (int nt = 0; nt < 8; ++nt) {
      float pm = 0.0f;   // relu outputs are >= 0
#pragma unroll
      for (int mt = 0; mt < 2; ++mt)
#pragma unroll
        for (int rr = 0; rr < 4; ++rr) {
          float y = (acc3[mt][nt][rr] + pb3[nt]) * ps3[nt] + pe3[nt];
          y = fmaxf(y, 0.0f);
          pm = fmaxf(pm, y);
        }
      pm = fmaxf(pm, __shfl_xor(pm, 16));
      pm = fmaxf(pm, __shfl_xor(pm, 32));
      if (q == 0) obuf[(nt * 16 + r) * 20 + ml] = pm;
    }
    __threadfence_block();
  }
  __syncthreads();
  // coalesced-ish store: thread t -> channel t>>1, half (t&1)*8
  {
    const int ch = t >> 1, mh = (t & 1) * 8;
    float4 u0 = *(const float4*)&obuf[ch * 20 + mh];
    float4 u1 = *(const float4*)&obuf[ch * 20 + mh + 4];
    float* outp = out + ((size_t)b * 128 + ch) * 1024 + m0 + mh;
    *(float4*)(outp)     = u0;
    *(float4*)(outp + 4) = u1;
  }
}

// ---------------------------------------------------------------------------
extern "C" void kernel_launch(void* const* d_in, const int* in_sizes, int n_in,
                              void* d_out, int out_size, void* d_ws, size_t ws_size,
                              hipStream_t stream) {
  (void)in_sizes; (void)n_in; (void)out_size; (void)ws_size;
  const float* points   = (const float*)d_in[0];
  const float* features = (const float*)d_in[1];
  const float* w1  = (const float*)d_in[2];
  const float* b1  = (const float*)d_in[3];
  const float* g1  = (const float*)d_in[4];
  const float* be1 = (const float*)d_in[5];
  const float* w2  = (const float*)d_in[6];
  const float* b2  = (const float*)d_in[7];
  const float* g2  = (const float*)d_in[8];
  const float* be2 = (const float*)d_in[9];
  const float* w3  = (const float*)d_in[10];
  const float* b3  = (const float*)d_in[11];
  const float* g3  = (const float*)d_in[12];
  const float* be3 = (const float*)d_in[13];

  float* outc = (float*)d_out;                  // centroids [16,3,1024]
  float* outf = outc + 16 * 3 * 1024;           // features  [16,128,1024]

  char* ws = (char*)d_ws;
  int*            nidx    = (int*)(ws);                      // 16384*32*4  = 2 MiB
  unsigned short* featsT  = (unsigned short*)(ws + 0x200000);// 16*4096*64*2= 8 MiB
  unsigned short* wpack   = (unsigned short*)(ws + 0xA00000);// 36*1024 B

  fused_pre<<<8 + 1024 + 9, 256, 0, stream>>>(points, features, w1, w2, w3,
                                              featsT, wpack, outc);
  ball_query_kernel<<<256, 256, 0, stream>>>(points, outc, nidx);
  mlp_kernel<<<1024, 256, 0, stream>>>(points, outc, nidx, featsT, wpack,
                                       b1, g1, be1, b2, g2, be2, b3, g3, be3, outf);
}

// Round 4
// 1286.578 us; speedup vs baseline: 1.4734x; 1.4734x over previous
//
#include <hip/hip_runtime.h>
#include <math.h>

#define NPTS 4096
#define MC   1024
#define KNB  32

typedef __attribute__((ext_vector_type(8))) short bf16x8;
typedef __attribute__((ext_vector_type(4))) float f32x4;

__device__ __forceinline__ unsigned short f2bf(float f) {
  unsigned int u = __float_as_uint(f);
  u = u + 0x7fffu + ((u >> 16) & 1u);   // round-to-nearest-even
  return (unsigned short)(u >> 16);
}

template <int CTRL>
__device__ __forceinline__ float dpp_max(float v) {
  int o = __builtin_amdgcn_update_dpp(__float_as_int(v), __float_as_int(v), CTRL, 0xF, 0xF, false);
  return fmaxf(v, __int_as_float(o));
}

// static-index 16->1 mux by mj bits (all indices compile-time -> stays in VGPRs)
#define MUX16(res, A)                                                     \
  {                                                                       \
    float p0 = s0_ ? A[1] : A[0],   p1 = s0_ ? A[3] : A[2];               \
    float p2 = s0_ ? A[5] : A[4],   p3 = s0_ ? A[7] : A[6];               \
    float p4 = s0_ ? A[9] : A[8],   p5 = s0_ ? A[11] : A[10];             \
    float p6 = s0_ ? A[13] : A[12], p7 = s0_ ? A[15] : A[14];             \
    float q0 = s1_ ? p1 : p0, q1 = s1_ ? p3 : p2;                         \
    float q2 = s1_ ? p5 : p4, q3 = s1_ ? p7 : p6;                         \
    float r0 = s2_ ? q1 : q0, r1 = s2_ ? q3 : q2;                         \
    res = s3_ ? r1 : r0;                                                  \
  }

// ---------------------------------------------------------------------------
// Kernel 1 (fused): blocks 0..15 = FPS, 16..1039 = feature transpose,
// 1040..1048 = weight pack.
//
// FPS R7 = R0's proven skeleton (256 thr, 4 waves, 16 pts/lane, barrier,
// non-volatile slot reads) + two register-neutral chain cuts proven correct
// in R2/R3:
//  (a) LANE-MAJOR ownership (lane t owns pts [16t,16t+16)) -> winner lane =
//      ONE ballot + ffs (lowest lane == lowest gidx), replacing R0's 16
//      ballots + SALU scan.
//  (b) coord PAYLOAD: winner lane muxes (x,y,z) from its own registers
//      (static cndmask tree) and publishes {key, xy, z} with the key ->
//      the dependent sx[sel]/sy[sel]/sz[sel] LDS trip and the 48KB coord
//      arrays are gone (LDS ~17KB).
// Sync stays publish -> ONE __syncthreads -> parallel non-volatile read of
// 4 key+payload slots, parity double-buffered (iter i+1's writes are gated
// by the next barrier, so slots for iter i can't be clobbered while read).
// NOT repeated here: R1 (8 waves: lockstep barrier cost), R2 (volatile
// spin: serialized LDS), R3 (batch pairing: register spill at 116 VGPR).
// Exact jnp.argmax semantics: strict-gt in-lane keeps lowest j; ffs keeps
// lowest lane; ~gidx in key low word keeps lowest gidx across waves; dist
// math bit-exact _rn.
// ---------------------------------------------------------------------------
struct FpsShared {
  unsigned long long key[2][4];   // [parity][wave]: distbits<<32 | ~gidx
  unsigned long long cxy[2][4];   // bits(y)<<32 | bits(x)
  float              cz [2][4];
  float slog[3][MC];
};
struct TransShared {
  float tile[64][65];
};

__global__ __launch_bounds__(256, 1) void fused_pre(
    const float* __restrict__ points, const float* __restrict__ feats,
    const float* __restrict__ w1, const float* __restrict__ w2,
    const float* __restrict__ w3,
    unsigned short* __restrict__ featsT, unsigned short* __restrict__ wpack,
    float* __restrict__ out_cent) {
  __shared__ union { FpsShared f; TransShared tr; } S;
  const int blk = blockIdx.x;
  const int t = threadIdx.x;

  if (blk < 16) {
    // ======================= FPS =======================
    const int b = blk;
    const int w = t >> 6, lane = t & 63;
    const float* pb = points + (size_t)b * 3 * NPTS;

    // lane-major: thread t owns global pts [16t, 16t+16); j = 4c+u
    float fx[16], fy[16], fz[16], dist[16];
#pragma unroll
    for (int c = 0; c < 4; ++c) {
      float4 X = ((const float4*)pb)[t * 4 + c];
      float4 Y = ((const float4*)(pb + NPTS))[t * 4 + c];
      float4 Z = ((const float4*)(pb + 2 * NPTS))[t * 4 + c];
      fx[c * 4 + 0] = X.x; fx[c * 4 + 1] = X.y; fx[c * 4 + 2] = X.z; fx[c * 4 + 3] = X.w;
      fy[c * 4 + 0] = Y.x; fy[c * 4 + 1] = Y.y; fy[c * 4 + 2] = Y.z; fy[c * 4 + 3] = Y.w;
      fz[c * 4 + 0] = Z.x; fz[c * 4 + 1] = Z.y; fz[c * 4 + 2] = Z.z; fz[c * 4 + 3] = Z.w;
    }
#pragma unroll
    for (int j = 0; j < 16; ++j) dist[j] = 1e10f;

    float lx = pb[0], ly = pb[NPTS], lz = pb[2 * NPTS];   // point 0 (uniform)

    for (int i = 0; i < MC; ++i) {
      if (t == 0) { S.f.slog[0][i] = lx; S.f.slog[1][i] = ly; S.f.slog[2][i] = lz; }
      if (i == MC - 1) break;

      // ---- distance update (bit-exact) + in-lane (max, lowest-j) ----
      float m = -1.0f;
      int mj = 0;
#pragma unroll
      for (int j = 0; j < 16; ++j) {
        float dx = __fsub_rn(fx[j], lx);
        float dy = __fsub_rn(fy[j], ly);
        float dz = __fsub_rn(fz[j], lz);
        float d  = __fadd_rn(__fadd_rn(__fmul_rn(dx, dx), __fmul_rn(dy, dy)), __fmul_rn(dz, dz));
        float dm = fminf(dist[j], d);
        dist[j] = dm;
        bool gt = dm > m;   // strict: keeps lowest j on ties
        m  = gt ? dm : m;
        mj = gt ? j  : mj;
      }

      // ---- wave value max via DPP (valid in lane 63) ----
      float mm = m;
      mm = dpp_max<0x111>(mm);   // row_shr:1
      mm = dpp_max<0x112>(mm);   // row_shr:2
      mm = dpp_max<0x114>(mm);   // row_shr:4
      mm = dpp_max<0x118>(mm);   // row_shr:8
      mm = dpp_max<0x142>(mm);   // row_bcast:15
      mm = dpp_max<0x143>(mm);   // row_bcast:31
      const float wv = __int_as_float(__builtin_amdgcn_readlane(__float_as_int(mm), 63));

      // ---- winner lane = lowest lane achieving wv (lane-major => lowest gidx) ----
      const unsigned long long ball = __ballot(m == wv);
      const int wl = __ffsll((long long)ball) - 1;
      const int par = i & 1;

      if (lane == wl) {
        const bool s0_ = mj & 1, s1_ = mj & 2, s2_ = mj & 4, s3_ = mj & 8;
        float wx, wy, wz;
        MUX16(wx, fx); MUX16(wy, fy); MUX16(wz, fz);
        const unsigned int gidx = (unsigned int)(t * 16 + mj);
        S.f.key[par][w] = ((unsigned long long)__float_as_uint(m) << 32) | (unsigned int)~gidx;
        S.f.cxy[par][w] = ((unsigned long long)__float_as_uint(wy) << 32) | __float_as_uint(wx);
        S.f.cz [par][w] = wz;
      }
      __syncthreads();

      // ---- one parallel LDS read of all 4 slots, payload tournament ----
      {
        unsigned long long k0 = S.f.key[par][0], k1 = S.f.key[par][1];
        unsigned long long k2 = S.f.key[par][2], k3 = S.f.key[par][3];
        unsigned long long x0 = S.f.cxy[par][0], x1 = S.f.cxy[par][1];
        unsigned long long x2 = S.f.cxy[par][2], x3 = S.f.cxy[par][3];
        float z0 = S.f.cz[par][0], z1 = S.f.cz[par][1];
        float z2 = S.f.cz[par][2], z3 = S.f.cz[par][3];
        const bool g1 = k1 > k0;
        const unsigned long long ka = g1 ? k1 : k0, xa = g1 ? x1 : x0; const float za = g1 ? z1 : z0;
        const bool g2 = k3 > k2;
        const unsigned long long kb = g2 ? k3 : k2, xb = g2 ? x3 : x2; const float zb = g2 ? z3 : z2;
        const bool g3 = kb > ka;
        const unsigned long long xw = g3 ? xb : xa;
        lx = __uint_as_float((unsigned int)xw);
        ly = __uint_as_float((unsigned int)(xw >> 32));
        lz = g3 ? zb : za;
      }
    }
    __syncthreads();
    // coalesced centroid output [3][1024] per batch
    float* oc = out_cent + (size_t)b * 3 * MC;
#pragma unroll
    for (int k = 0; k < 12; ++k) {
      int idx = t + k * 256;
      oc[idx] = ((const float*)S.f.slog)[idx];
    }
  } else if (blk < 16 + 1024) {
    // ================== feature transpose ==================
    const int rel = blk - 16;
    const int b = rel >> 6;
    const int n0 = (rel & 63) * 64;
    const float* src = feats + (size_t)b * 64 * NPTS;
    {
      const int n = t & 63, cbase = t >> 6;
#pragma unroll
      for (int j = 0; j < 16; ++j) {
        int cc = cbase + j * 4;
        S.tr.tile[cc][n] = src[(size_t)cc * NPTS + n0 + n];
      }
    }
    __syncthreads();
    {
      const int cc = t & 63, nbase = t >> 6;
      unsigned short* dst = featsT + ((size_t)b * NPTS + n0) * 64;
#pragma unroll
      for (int j = 0; j < 16; ++j) {
        int n = nbase + j * 4;
        dst[(size_t)n * 64 + cc] = f2bf(S.tr.tile[cc][n]);
      }
    }
  } else {
    // ================== weight pack (f = 0..35) ==================
    const int f = (blk - (16 + 1024)) * 4 + (t >> 6);
    const int lane = t & 63;
    if (f < 36) {
      int layer, kt, nt;
      if (f < 12)      { layer = 0; kt = f >> 2;        nt = f & 3; }
      else if (f < 20) { layer = 1; kt = (f - 12) >> 2; nt = (f - 12) & 3; }
      else             { layer = 2; kt = (f - 20) >> 3; nt = (f - 20) & 7; }
      const int o = nt * 16 + (lane & 15);
      unsigned short* dst = wpack + ((size_t)f * 64 + lane) * 8;
#pragma unroll
      for (int j = 0; j < 8; ++j) {
        int k = kt * 32 + (lane >> 4) * 8 + j;
        float x = 0.0f;
        if (layer == 0)      { if (k < 67) { int cin = (k < 64) ? (k + 3) : (k - 64); x = w1[o * 67 + cin]; } }
        else if (layer == 1) { x = w2[o * 64 + k]; }
        else                 { x = w3[o * 64 + k]; }
        dst[j] = f2bf(x);
      }
    }
  }
}

// ---------------------------------------------------------------------------
// Kernel 2: ball query. Centroids read from out_cent layout [B,3,MC].
// ---------------------------------------------------------------------------
__global__ __launch_bounds__(256) void ball_query_kernel(const float* __restrict__ points,
                                                         const float* __restrict__ cent,
                                                         int* __restrict__ nidx) {
  __shared__ float sx[NPTS], sy[NPTS], sz[NPTS];
  __shared__ int lists[4][KNB];
  const int b  = blockIdx.x >> 4;
  const int cb = blockIdx.x & 15;
  const int t = threadIdx.x;
  const float* pb = points + (size_t)b * 3 * NPTS;
#pragma unroll
  for (int j = 0; j < 4; ++j) {
    int i4 = t + j * 256;
    ((float4*)sx)[i4] = ((const float4*)pb)[i4];
    ((float4*)sy)[i4] = ((const float4*)(pb + NPTS))[i4];
    ((float4*)sz)[i4] = ((const float4*)(pb + 2 * NPTS))[i4];
  }
  __syncthreads();
  const int w = t >> 6, lane = t & 63;
  const float R2 = (float)(0.2 * 0.2);
  const float* cbp = cent + (size_t)b * 3 * MC;
  for (int cm = 0; cm < 16; ++cm) {
    const int m  = cb * 64 + w * 16 + cm;
    const int bm = b * MC + m;
    const float cx = cbp[m], cy = cbp[MC + m], cz = cbp[2 * MC + m];
    const float c2 = __fadd_rn(__fadd_rn(__fmul_rn(cx, cx), __fmul_rn(cy, cy)), __fmul_rn(cz, cz));
    int cnt = 0;
    for (int ch = 0; ch < 64; ++ch) {
      const int n = ch * 64 + lane;
      float x = sx[n], y = sy[n], z = sz[n];
      float p2  = __fadd_rn(__fadd_rn(__fmul_rn(x, x),  __fmul_rn(y, y)),  __fmul_rn(z, z));
      float dot = __fadd_rn(__fadd_rn(__fmul_rn(cx, x), __fmul_rn(cy, y)), __fmul_rn(cz, z));
      float d2  = __fsub_rn(__fadd_rn(c2, p2), __fmul_rn(2.0f, dot));
      bool hit = (d2 <= R2);
      unsigned long long msk = __ballot(hit);
      if (hit) {
        int pos = cnt + __popcll(msk & ((1ull << lane) - 1ull));
        if (pos < KNB) lists[w][pos] = n;
      }
      cnt += __popcll(msk);
      if (cnt >= KNB) break;
    }
    if (lane < KNB) {
      int first = lists[w][0];
      int v = (lane < cnt) ? lists[w][lane] : first;
      nidx[(size_t)bm * KNB + lane] = v;
    }
  }
}

// ---------------------------------------------------------------------------
// Kernel 3: fused gather + 3-layer MLP (bf16 MFMA 16x16x32) + maxpool.
// ---------------------------------------------------------------------------
__global__ __launch_bounds__(256) void mlp_kernel(
    const float* __restrict__ points,
    const float* __restrict__ cent,
    const int* __restrict__ nidx,
    const unsigned short* __restrict__ featsT,
    const unsigned short* __restrict__ wpack,
    const float* __restrict__ b1, const float* __restrict__ g1, const float* __restrict__ be1,
    const float* __restrict__ b2, const float* __restrict__ g2, const float* __restrict__ be2,
    const float* __restrict__ b3, const float* __restrict__ g3, const float* __restrict__ be3,
    float* __restrict__ out) {
  __shared__ __align__(16) unsigned short Hs[4][2][32 * 72];
  __shared__ __align__(16) float obuf[128 * 20];
  const int t = threadIdx.x;
  const int w = t >> 6, lane = t & 63;
  const int r = lane & 15, q = lane >> 4;
  const float inv_s = 1.0f / sqrtf(1.0f + 1e-5f);

  float pb1[4], ps1[4], pe1[4], pb2[4], ps2[4], pe2[4], pb3[8], ps3[8], pe3[8];
#pragma unroll
  for (int nt = 0; nt < 4; ++nt) {
    int o = nt * 16 + r;
    pb1[nt] = b1[o]; ps1[nt] = g1[o] * inv_s; pe1[nt] = be1[o];
    pb2[nt] = b2[o]; ps2[nt] = g2[o] * inv_s; pe2[nt] = be2[o];
  }
#pragma unroll
  for (int nt = 0; nt < 8; ++nt) {
    int o = nt * 16 + r;
    pb3[nt] = b3[o]; ps3[nt] = g3[o] * inv_s; pe3[nt] = be3[o];
  }
  const int bm0 = blockIdx.x * 16;
  const int b   = bm0 >> 10;
  const int m0  = bm0 & 1023;
  const float* ptsb = points + (size_t)b * 3 * NPTS;
  const float* cbp  = cent + (size_t)b * 3 * MC;

  for (int it = 0; it < 4; ++it) {
    const int ml = it * 4 + w;
    const int bm = bm0 + ml;
    const int m  = bm & 1023;
    const int n0 = nidx[(size_t)bm * KNB + r];
    const int n1 = nidx[(size_t)bm * KNB + 16 + r];
    const float cx = cbp[m], cy = cbp[MC + m], cz = cbp[2 * MC + m];

    // ---- layer 1 ----
    bf16x8 aF[2][2];
#pragma unroll
    for (int mt = 0; mt < 2; ++mt) {
      int n = mt ? n1 : n0;
      const unsigned short* rowp = featsT + ((size_t)b * NPTS + n) * 64 + q * 8;
      aF[mt][0] = *(const bf16x8*)(rowp);
      aF[mt][1] = *(const bf16x8*)(rowp + 32);
    }
    bf16x8 aL[2];
#pragma unroll
    for (int mt = 0; mt < 2; ++mt) {
      bf16x8 a = {0, 0, 0, 0, 0, 0, 0, 0};
      if (q == 0) {
        int n = mt ? n1 : n0;
        a[0] = (short)f2bf(ptsb[n] - cx);
        a[1] = (short)f2bf(ptsb[NPTS + n] - cy);
        a[2] = (short)f2bf(ptsb[2 * NPTS + n] - cz);
      }
      aL[mt] = a;
    }
    f32x4 acc1[2][4];
#pragma unroll
    for (int mt = 0; mt < 2; ++mt)
#pragma unroll
      for (int nt = 0; nt < 4; ++nt) acc1[mt][nt] = (f32x4){0.f, 0.f, 0.f, 0.f};
#pragma unroll
    for (int kt = 0; kt < 3; ++kt) {
#pragma unroll
      for (int nt = 0; nt < 4; ++nt) {
        bf16x8 wf = *(const bf16x8*)(wpack + ((size_t)(kt * 4 + nt) * 64 + lane) * 8);
#pragma unroll
        for (int mt = 0; mt < 2; ++mt) {
          bf16x8 a = (kt < 2) ? aF[mt][kt] : aL[mt];
          acc1[mt][nt] = __builtin_amdgcn_mfma_f32_16x16x32_bf16(a, wf, acc1[mt][nt], 0, 0, 0);
        }
      }
    }
#pragma unroll
    for (int mt = 0; mt < 2; ++mt)
#pragma unroll
      for (int nt = 0; nt < 4; ++nt)
#pragma unroll
        for (int rr = 0; rr < 4; ++rr) {
          float y = (acc1[mt][nt][rr] + pb1[nt]) * ps1[nt] + pe1[nt];
          y = fmaxf(y, 0.0f);
          Hs[w][0][(mt * 16 + q * 4 + rr) * 72 + nt * 16 + r] = f2bf(y);
        }
    __threadfence_block();

    // ---- layer 2 ----
    f32x4 acc2[2][4];
#pragma unroll
    for (int mt = 0; mt < 2; ++mt)
#pragma unroll
      for (int nt = 0; nt < 4; ++nt) acc2[mt][nt] = (f32x4){0.f, 0.f, 0.f, 0.f};
#pragma unroll
    for (int kt = 0; kt < 2; ++kt) {
      bf16x8 a0 = *(const bf16x8*)&Hs[w][0][(0 * 16 + r) * 72 + kt * 32 + q * 8];
      bf16x8 a1 = *(const bf16x8*)&Hs[w][0][(1 * 16 + r) * 72 + kt * 32 + q * 8];
#pragma unroll
      for (int nt = 0; nt < 4; ++nt) {
        bf16x8 wf = *(const bf16x8*)(wpack + ((size_t)(12 + kt * 4 + nt) * 64 + lane) * 8);
        acc2[0][nt] = __builtin_amdgcn_mfma_f32_16x16x32_bf16(a0, wf, acc2[0][nt], 0, 0, 0);
        acc2[1][nt] = __builtin_amdgcn_mfma_f32_16x16x32_bf16(a1, wf, acc2[1][nt], 0, 0, 0);
      }
    }
#pragma unroll
    for (int mt = 0; mt < 2; ++mt)
#pragma unroll
      for (int nt = 0; nt < 4; ++nt)
#pragma unroll
        for (int rr = 0; rr < 4; ++rr) {
          float y = (acc2[mt][nt][rr] + pb2[nt]) * ps2[nt] + pe2[nt];
          y = fmaxf(y, 0.0f);
          Hs[w][1][(mt * 16 + q * 4 + rr) * 72 + nt * 16 + r] = f2bf(y);
        }
    __threadfence_block();

    // ---- layer 3 + maxpool ----
    f32x4 acc3[2][8];
#pragma unroll
    for (int mt = 0; mt < 2; ++mt)
#pragma unroll
      for (int nt = 0; nt < 8; ++nt) acc3[mt][nt] = (f32x4){0.f, 0.f, 0.f, 0.f};
#pragma unroll
    for (int kt = 0; kt < 2; ++kt) {
      bf16x8 a0 = *(const bf16x8*)&Hs[w][1][(0 * 16 + r) * 72 + kt * 32 + q * 8];
      bf16x8 a1 = *(const bf16x8*)&Hs[w][1][(1 * 16 + r) * 72 + kt * 32 + q * 8];
#pragma unroll
      for (int nt = 0; nt < 8; ++nt) {
        bf16x8 wf = *(const bf16x8*)(wpack + ((size_t)(20 + kt * 8 + nt) * 64 + lane) * 8);
        acc3[0][nt] = __builtin_amdgcn_mfma_f32_16x16x32_bf16(a0, wf, acc3[0][nt], 0, 0, 0);
        acc3[1][nt] = __builtin_amdgcn_mfma_f32_16x16x32_bf16(a1, wf, acc3[1][nt], 0, 0, 0);
      }
    }
#pragma unroll
    for (int nt = 0; nt < 8; ++nt) {
      float pm = 0.0f;   // relu outputs are >= 0
#pragma unroll
      for (int mt = 0; mt < 2; ++mt)
#pragma unroll
        for (int rr = 0; rr < 4; ++rr) {
          float y = (acc3[mt][nt][rr] + pb3[nt]) * ps3[nt] + pe3[nt];
          y = fmaxf(y, 0.0f);
          pm = fmaxf(pm, y);
        }
      pm = fmaxf(pm, __shfl_xor(pm, 16));
      pm = fmaxf(pm, __shfl_xor(pm, 32));
      if (q == 0) obuf[(nt * 16 + r) * 20 + ml] = pm;
    }
    __threadfence_block();
  }
  __syncthreads();
  // coalesced-ish store: thread t -> channel t>>1, half (t&1)*8
  {
    const int ch = t >> 1, mh = (t & 1) * 8;
    float4 u0 = *(const float4*)&obuf[ch * 20 + mh];
    float4 u1 = *(const float4*)&obuf[ch * 20 + mh + 4];
    float* outp = out + ((size_t)b * 128 + ch) * 1024 + m0 + mh;
    *(float4*)(outp)     = u0;
    *(float4*)(outp + 4) = u1;
  }
}

// ---------------------------------------------------------------------------
extern "C" void kernel_launch(void* const* d_in, const int* in_sizes, int n_in,
                              void* d_out, int out_size, void* d_ws, size_t ws_size,
                              hipStream_t stream) {
  (void)in_sizes; (void)n_in; (void)out_size; (void)ws_size;
  const float* points   = (const float*)d_in[0];
  const float* features = (const float*)d_in[1];
  const float* w1  = (const float*)d_in[2];
  const float* b1  = (const float*)d_in[3];
  const float* g1  = (const float*)d_in[4];
  const float* be1 = (const float*)d_in[5];
  const float* w2  = (const float*)d_in[6];
  const float* b2  = (const float*)d_in[7];
  const float* g2  = (const float*)d_in[8];
  const float* be2 = (const float*)d_in[9];
  const float* w3  = (const float*)d_in[10];
  const float* b3  = (const float*)d_in[11];
  const float* g3  = (const float*)d_in[12];
  const float* be3 = (const float*)d_in[13];

  float* outc = (float*)d_out;                  // centroids [16,3,1024]
  float* outf = outc + 16 * 3 * 1024;           // features  [16,128,1024]

  char* ws = (char*)d_ws;
  int*            nidx    = (int*)(ws);                      // 16384*32*4  = 2 MiB
  unsigned short* featsT  = (unsigned short*)(ws + 0x200000);// 16*4096*64*2= 8 MiB
  unsigned short* wpack   = (unsigned short*)(ws + 0xA00000);// 36*1024 B

  fused_pre<<<16 + 1024 + 9, 256, 0, stream>>>(points, features, w1, w2, w3,
                                               featsT, wpack, outc);
  ball_query_kernel<<<256, 256, 0, stream>>>(points, outc, nidx);
  mlp_kernel<<<1024, 256, 0, stream>>>(points, outc, nidx, featsT, wpack,
                                       b1, g1, be1, b2, g2, be2, b3, g3, be3, outf);
}